// Round 8
// baseline (532.157 us; speedup 1.0000x reference)
//
#include <hip/hip_runtime.h>
#include <hip/hip_bf16.h>

#define NG 8
#define NT 4096
#define DIN 1024
#define DOUT 4096
#define BM 128
#define BN 128
#define BK 64
#define KTILES (DIN / BK)   // 16

typedef __attribute__((ext_vector_type(4))) float f32x4;
typedef __attribute__((ext_vector_type(8))) short bf16x8;

// swizzled byte offset within a [rows][BK] bf16 LDS tile (row pitch 128B);
// XOR row&7 into the 16B-chunk bits -> conflict-free b128 frag reads (measured 0)
__device__ __forceinline__ int swz(int row, int colb) {
    return row * (BK * 2) + (colb ^ ((row & 7) << 4));
}

// 4 f32 -> 8B packed bf16 (compiler emits v_cvt_pk_bf16_f32 pairs)
__device__ __forceinline__ unsigned long long pack4bf(f32x4 v) {
    union { __hip_bfloat16 h; unsigned short u; } c0, c1, c2, c3;
    c0.h = __float2bfloat16(v[0]);
    c1.h = __float2bfloat16(v[1]);
    c2.h = __float2bfloat16(v[2]);
    c3.h = __float2bfloat16(v[3]);
    return (unsigned long long)c0.u | ((unsigned long long)c1.u << 16) |
           ((unsigned long long)c2.u << 32) | ((unsigned long long)c3.u << 48);
}

// launch_bounds(256,4): 4 waves/EU -> 4 blocks/CU target (VGPR cap 128; was 124).
// 32KB LDS allows 5 blocks/CU; occupancy experiment vs R6's (256,2).
__global__ __launch_bounds__(256, 4)
void grouped_gemm_bf16(const float* __restrict__ x,
                       const int* __restrict__ offs,
                       const float* __restrict__ w,
                       float* __restrict__ out) {
    // single buffer, bf16: A 16KB + B 16KB = 32KB
    __shared__ char lds[2 * BM * BK * 2];
    char* lA = lds;
    char* lB = lds + BM * BK * 2;

    // ---- map blockIdx.y -> (group, row0), group-aligned row tiles ----
    const int rt = blockIdx.y;
    const int n0 = blockIdx.x * BN;
    int row0 = 0, endg = 0, gsel = -1;
    {
        int acc = 0, prev = 0;
        for (int g = 0; g < NG; ++g) {
            int e = offs[g];
            int cnt = (e - prev + BM - 1) / BM;
            if (rt < acc + cnt) { gsel = g; row0 = prev + (rt - acc) * BM; endg = e; break; }
            acc += cnt; prev = e;
        }
    }
    if (gsel < 0) return;
    const float* wg = w + (size_t)gsel * DOUT * DIN;

    const int tid  = threadIdx.x;
    const int lane = tid & 63;
    const int wid  = tid >> 6;
    const int wr   = wid >> 1, wc = wid & 1;     // 2x2 wave grid
    const int lrow = lane & 15, kgrp = lane >> 4;
    const int sr   = tid >> 4;                   // staging row base (0..15)
    const int sc4  = tid & 15;                   // staging float4 col

    // staging source offsets (OOB A-rows clamped; outputs masked at C-store)
    int aoff[8], boff[8];
    #pragma unroll
    for (int i = 0; i < 8; ++i) {
        int r = sr + i * 16;
        int ar = row0 + r; if (ar >= endg) ar = endg - 1;
        aoff[i] = ar * DIN + sc4 * 4;
        boff[i] = (n0 + r) * DIN + sc4 * 4;
    }

    f32x4 acc[4][4];
    #pragma unroll
    for (int m = 0; m < 4; ++m)
        #pragma unroll
        for (int n = 0; n < 4; ++n)
            acc[m][n] = (f32x4){0.f, 0.f, 0.f, 0.f};

    f32x4 pA[8], pB[8];

    // ---- prologue: load + stage tile 0 ----
    #pragma unroll
    for (int i = 0; i < 8; ++i) pA[i] = *(const f32x4*)(x + aoff[i]);
    #pragma unroll
    for (int i = 0; i < 8; ++i) pB[i] = *(const f32x4*)(wg + boff[i]);
    #pragma unroll
    for (int i = 0; i < 8; ++i)
        *(unsigned long long*)(lA + swz(sr + i * 16, sc4 * 8)) = pack4bf(pA[i]);
    #pragma unroll
    for (int i = 0; i < 8; ++i)
        *(unsigned long long*)(lB + swz(sr + i * 16, sc4 * 8)) = pack4bf(pB[i]);
    __syncthreads();

    for (int kt = 0; kt < KTILES; ++kt) {
        // ---- issue next tile's 16 global loads, then FENCE so the scheduler
        //      cannot sink them below compute ----
        if (kt + 1 < KTILES) {
            const int k0 = (kt + 1) * BK;
            #pragma unroll
            for (int i = 0; i < 8; ++i) pA[i] = *(const f32x4*)(x + aoff[i] + k0);
            #pragma unroll
            for (int i = 0; i < 8; ++i) pB[i] = *(const f32x4*)(wg + boff[i] + k0);
            __builtin_amdgcn_sched_barrier(0);
        }

        // ---- compute current tile from bf16 LDS ----
        #pragma unroll
        for (int kk = 0; kk < 2; ++kk) {
            const int kb = kk * 64 + kgrp * 16;
            bf16x8 af[4], bb[4];
            #pragma unroll
            for (int m = 0; m < 4; ++m)
                af[m] = *(const bf16x8*)(lA + swz(wr * 64 + m * 16 + lrow, kb));
            #pragma unroll
            for (int n = 0; n < 4; ++n)
                bb[n] = *(const bf16x8*)(lB + swz(wc * 64 + n * 16 + lrow, kb));
            #pragma unroll
            for (int m = 0; m < 4; ++m)
                #pragma unroll
                for (int n = 0; n < 4; ++n)
                    acc[m][n] = __builtin_amdgcn_mfma_f32_16x16x32_bf16(
                        af[m], bb[n], acc[m][n], 0, 0, 0);
        }
        __syncthreads();   // all waves done reading this tile

        // ---- overwrite LDS with next tile (cvt_pk + ds_write), make visible ----
        if (kt + 1 < KTILES) {
            #pragma unroll
            for (int i = 0; i < 8; ++i)
                *(unsigned long long*)(lA + swz(sr + i * 16, sc4 * 8)) = pack4bf(pA[i]);
            #pragma unroll
            for (int i = 0; i < 8; ++i)
                *(unsigned long long*)(lB + swz(sr + i * 16, sc4 * 8)) = pack4bf(pB[i]);
            __syncthreads();
        }
    }

    // ---- epilogue: C/D layout col=lane&15, row=(lane>>4)*4+j ----
    #pragma unroll
    for (int m = 0; m < 4; ++m) {
        #pragma unroll
        for (int j = 0; j < 4; ++j) {
            int row = row0 + wr * 64 + m * 16 + kgrp * 4 + j;
            if (row < endg) {
                #pragma unroll
                for (int n = 0; n < 4; ++n) {
                    int col = n0 + wc * 64 + n * 16 + lrow;
                    out[(size_t)row * DOUT + col] = acc[m][n][j];
                }
            }
        }
    }
}

extern "C" void kernel_launch(void* const* d_in, const int* in_sizes, int n_in,
                              void* d_out, int out_size, void* d_ws, size_t ws_size,
                              hipStream_t stream) {
    const float* x    = (const float*)d_in[0];
    const int*   offs = (const int*)d_in[1];
    const float* w    = (const float*)d_in[2];
    float* out = (float*)d_out;

    dim3 grid(DOUT / BN, NT / BM + NG, 1);
    grouped_gemm_bf16<<<grid, 256, 0, stream>>>(x, offs, w, out);
}

// Round 9
// 136.805 us; speedup vs baseline: 3.8899x; 3.8899x over previous
//
#include <hip/hip_runtime.h>
#include <hip/hip_bf16.h>

#define NG 8
#define NT 4096
#define DIN 1024
#define DOUT 4096
#define BM 256
#define BN 256
#define BK 64
#define KTILES (DIN / BK)   // 16
#define THREADS 512

typedef __attribute__((ext_vector_type(4))) float f32x4;
typedef __attribute__((ext_vector_type(8))) short bf16x8;

// swizzled byte offset within a [rows][BK=64] bf16 LDS tile (row pitch 128B);
// XOR row&7 into the 16B-chunk bits -> conflict-free b128 frag reads (measured 0)
__device__ __forceinline__ int swz(int row, int colb) {
    return row * (BK * 2) + (colb ^ ((row & 7) << 4));
}

// 4 f32 -> 8B packed bf16 (compiler emits v_cvt_pk_bf16_f32 pairs)
__device__ __forceinline__ unsigned long long pack4bf(f32x4 v) {
    union { __hip_bfloat16 h; unsigned short u; } c0, c1, c2, c3;
    c0.h = __float2bfloat16(v[0]);
    c1.h = __float2bfloat16(v[1]);
    c2.h = __float2bfloat16(v[2]);
    c3.h = __float2bfloat16(v[3]);
    return (unsigned long long)c0.u | ((unsigned long long)c1.u << 16) |
           ((unsigned long long)c2.u << 32) | ((unsigned long long)c3.u << 48);
}

__global__ __launch_bounds__(THREADS, 2)
void grouped_gemm_bf16(const float* __restrict__ x,
                       const int* __restrict__ offs,
                       const float* __restrict__ w,
                       float* __restrict__ out) {
    // single buffer, bf16: A 32KB + B 32KB = 64KB
    __shared__ char lds[2 * BM * BK * 2];
    char* lA = lds;
    char* lB = lds + BM * BK * 2;

    // ---- map blockIdx.y -> (group, row0), group-aligned 256-row tiles ----
    const int rt = blockIdx.y;
    const int n0 = blockIdx.x * BN;
    int row0 = 0, endg = 0, gsel = -1;
    {
        int acc = 0, prev = 0;
        for (int g = 0; g < NG; ++g) {
            int e = offs[g];
            int cnt = (e - prev + BM - 1) / BM;
            if (rt < acc + cnt) { gsel = g; row0 = prev + (rt - acc) * BM; endg = e; break; }
            acc += cnt; prev = e;
        }
    }
    if (gsel < 0) return;
    const float* wg = w + (size_t)gsel * DOUT * DIN;

    const int tid  = threadIdx.x;
    const int lane = tid & 63;
    const int wid  = tid >> 6;                  // 0..7
    const int wr   = wid >> 2, wc = wid & 3;    // 2x4 wave grid; wave tile 128x64
    const int lrow = lane & 15, kgrp = lane >> 4;
    const int sr   = tid >> 4;                  // staging row base (0..31)
    const int sc4  = tid & 15;                  // staging float4 col (0..15)

    // staging source offsets: rows sr + i*32 (i=0..7) cover 256 rows
    int aoff[8], boff[8];
    #pragma unroll
    for (int i = 0; i < 8; ++i) {
        int r = sr + i * 32;
        int ar = row0 + r; if (ar >= endg) ar = endg - 1;   // clamp; masked at store
        aoff[i] = ar * DIN + sc4 * 4;
        boff[i] = (n0 + r) * DIN + sc4 * 4;
    }

    f32x4 acc[8][4];
    #pragma unroll
    for (int m = 0; m < 8; ++m)
        #pragma unroll
        for (int n = 0; n < 4; ++n)
            acc[m][n] = (f32x4){0.f, 0.f, 0.f, 0.f};

    f32x4 pA[8], pB[8];

    // ---- prologue: load + stage tile 0 ----
    #pragma unroll
    for (int i = 0; i < 8; ++i) pA[i] = *(const f32x4*)(x + aoff[i]);
    #pragma unroll
    for (int i = 0; i < 8; ++i) pB[i] = *(const f32x4*)(wg + boff[i]);
    #pragma unroll
    for (int i = 0; i < 8; ++i)
        *(unsigned long long*)(lA + swz(sr + i * 32, sc4 * 8)) = pack4bf(pA[i]);
    #pragma unroll
    for (int i = 0; i < 8; ++i)
        *(unsigned long long*)(lB + swz(sr + i * 32, sc4 * 8)) = pack4bf(pB[i]);
    __syncthreads();

    for (int kt = 0; kt < KTILES; ++kt) {
        // ---- issue next tile's 16 global loads; fence keeps them hoisted ----
        if (kt + 1 < KTILES) {
            const int k0 = (kt + 1) * BK;
            #pragma unroll
            for (int i = 0; i < 8; ++i) pA[i] = *(const f32x4*)(x + aoff[i] + k0);
            #pragma unroll
            for (int i = 0; i < 8; ++i) pB[i] = *(const f32x4*)(wg + boff[i] + k0);
            __builtin_amdgcn_sched_barrier(0);
        }

        // ---- compute: wave tile 128x64; A frags cached, B frag streamed ----
        #pragma unroll
        for (int kk = 0; kk < 2; ++kk) {
            const int kb = kk * 64 + kgrp * 16;
            bf16x8 af[8];
            #pragma unroll
            for (int m = 0; m < 8; ++m)
                af[m] = *(const bf16x8*)(lA + swz(wr * 128 + m * 16 + lrow, kb));
            #pragma unroll
            for (int n = 0; n < 4; ++n) {
                bf16x8 bb = *(const bf16x8*)(lB + swz(wc * 64 + n * 16 + lrow, kb));
                #pragma unroll
                for (int m = 0; m < 8; ++m)
                    acc[m][n] = __builtin_amdgcn_mfma_f32_16x16x32_bf16(
                        af[m], bb, acc[m][n], 0, 0, 0);
            }
        }
        __syncthreads();   // all waves done reading this tile

        // ---- overwrite LDS with next tile (cvt_pk + ds_write) ----
        if (kt + 1 < KTILES) {
            #pragma unroll
            for (int i = 0; i < 8; ++i)
                *(unsigned long long*)(lA + swz(sr + i * 32, sc4 * 8)) = pack4bf(pA[i]);
            #pragma unroll
            for (int i = 0; i < 8; ++i)
                *(unsigned long long*)(lB + swz(sr + i * 32, sc4 * 8)) = pack4bf(pB[i]);
            __syncthreads();
        }
    }

    // ---- epilogue: C/D layout col=lane&15, row=(lane>>4)*4+j ----
    #pragma unroll
    for (int m = 0; m < 8; ++m) {
        #pragma unroll
        for (int j = 0; j < 4; ++j) {
            int row = row0 + wr * 128 + m * 16 + kgrp * 4 + j;
            if (row < endg) {
                #pragma unroll
                for (int n = 0; n < 4; ++n) {
                    int col = n0 + wc * 64 + n * 16 + lrow;
                    out[(size_t)row * DOUT + col] = acc[m][n][j];
                }
            }
        }
    }
}

extern "C" void kernel_launch(void* const* d_in, const int* in_sizes, int n_in,
                              void* d_out, int out_size, void* d_ws, size_t ws_size,
                              hipStream_t stream) {
    const float* x    = (const float*)d_in[0];
    const int*   offs = (const int*)d_in[1];
    const float* w    = (const float*)d_in[2];
    float* out = (float*)d_out;

    // y-slots = NT/BM + NG (worst-case sum of per-group ceils)
    dim3 grid(DOUT / BN, NT / BM + NG, 1);
    grouped_gemm_bf16<<<grid, THREADS, 0, stream>>>(x, offs, w, out);
}

// Round 10
// 82.676 us; speedup vs baseline: 6.4366x; 1.6547x over previous
//
#include <hip/hip_runtime.h>
#include <hip/hip_bf16.h>

#define NG 8
#define NT 4096
#define DIN 1024
#define DOUT 4096
#define BM 128
#define BN 128
#define BK 64
#define KTILES (DIN / BK)   // 16
#define TILESZ (BM * BK * 2)        // one bf16 tile: 16KB
#define BUFSZ  (2 * TILESZ)         // A+B: 32KB per buffer

typedef __attribute__((ext_vector_type(4))) float f32x4;
typedef __attribute__((ext_vector_type(8))) short bf16x8;

// swizzled byte offset within a [rows][BK] bf16 LDS tile (row pitch 128B);
// XOR row&7 into the 16B-chunk bits -> conflict-free b128 frag reads (measured 0)
__device__ __forceinline__ int swz(int row, int colb) {
    return row * (BK * 2) + (colb ^ ((row & 7) << 4));
}

// 4 f32 -> 8B packed bf16 (compiler emits v_cvt_pk_bf16_f32 pairs)
__device__ __forceinline__ unsigned long long pack4bf(f32x4 v) {
    union { __hip_bfloat16 h; unsigned short u; } c0, c1, c2, c3;
    c0.h = __float2bfloat16(v[0]);
    c1.h = __float2bfloat16(v[1]);
    c2.h = __float2bfloat16(v[2]);
    c3.h = __float2bfloat16(v[3]);
    return (unsigned long long)c0.u | ((unsigned long long)c1.u << 16) |
           ((unsigned long long)c2.u << 32) | ((unsigned long long)c3.u << 48);
}

__global__ __launch_bounds__(256, 2)
void grouped_gemm_bf16(const float* __restrict__ x,
                       const int* __restrict__ offs,
                       const float* __restrict__ w,
                       float* __restrict__ out) {
    // double buffer, bf16: 2 x (A 16KB + B 16KB) = 64KB
    __shared__ char lds[2 * BUFSZ];

    // ---- map blockIdx.y -> (group, row0), group-aligned row tiles ----
    const int rt = blockIdx.y;
    const int n0 = blockIdx.x * BN;
    int row0 = 0, endg = 0, gsel = -1;
    {
        int acc = 0, prev = 0;
        for (int g = 0; g < NG; ++g) {
            int e = offs[g];
            int cnt = (e - prev + BM - 1) / BM;
            if (rt < acc + cnt) { gsel = g; row0 = prev + (rt - acc) * BM; endg = e; break; }
            acc += cnt; prev = e;
        }
    }
    if (gsel < 0) return;
    const float* wg = w + (size_t)gsel * DOUT * DIN;

    const int tid  = threadIdx.x;
    const int lane = tid & 63;
    const int wid  = tid >> 6;
    const int wr   = wid >> 1, wc = wid & 1;     // 2x2 wave grid
    const int lrow = lane & 15, kgrp = lane >> 4;
    const int sr   = tid >> 4;                   // staging row base (0..15)
    const int sc4  = tid & 15;                   // staging float4 col

    // staging source offsets (OOB A-rows clamped; outputs masked at C-store)
    int aoff[8], boff[8];
    #pragma unroll
    for (int i = 0; i < 8; ++i) {
        int r = sr + i * 16;
        int ar = row0 + r; if (ar >= endg) ar = endg - 1;
        aoff[i] = ar * DIN + sc4 * 4;
        boff[i] = (n0 + r) * DIN + sc4 * 4;
    }

    f32x4 acc[4][4];
    #pragma unroll
    for (int m = 0; m < 4; ++m)
        #pragma unroll
        for (int n = 0; n < 4; ++n)
            acc[m][n] = (f32x4){0.f, 0.f, 0.f, 0.f};

    f32x4 pA[8], pB[8];

    // ---- prologue: load + stage tile 0 into buf 0 ----
    #pragma unroll
    for (int i = 0; i < 8; ++i) pA[i] = *(const f32x4*)(x + aoff[i]);
    #pragma unroll
    for (int i = 0; i < 8; ++i) pB[i] = *(const f32x4*)(wg + boff[i]);
    {
        char* sA = lds;
        char* sB = lds + TILESZ;
        #pragma unroll
        for (int i = 0; i < 8; ++i)
            *(unsigned long long*)(sA + swz(sr + i * 16, sc4 * 8)) = pack4bf(pA[i]);
        #pragma unroll
        for (int i = 0; i < 8; ++i)
            *(unsigned long long*)(sB + swz(sr + i * 16, sc4 * 8)) = pack4bf(pB[i]);
    }
    asm volatile("s_waitcnt lgkmcnt(0)" ::: "memory");
    __builtin_amdgcn_sched_barrier(0);
    __builtin_amdgcn_s_barrier();
    __builtin_amdgcn_sched_barrier(0);

    for (int kt = 0; kt < KTILES; ++kt) {
        const int cur = kt & 1;
        char* lA = lds + cur * BUFSZ;
        char* lB = lA + TILESZ;

        // ---- issue next tile's 16 global loads to regs; NO drain anywhere —
        //      the compiler's vmcnt before the consuming cvt (post-compute)
        //      is the only wait, so HBM latency hides under the MFMA phase ----
        if (kt + 1 < KTILES) {
            const int k0 = (kt + 1) * BK;
            #pragma unroll
            for (int i = 0; i < 8; ++i) pA[i] = *(const f32x4*)(x + aoff[i] + k0);
            #pragma unroll
            for (int i = 0; i < 8; ++i) pB[i] = *(const f32x4*)(wg + boff[i] + k0);
            __builtin_amdgcn_sched_barrier(0);
        }

        // ---- compute current tile from bf16 LDS buf[cur] ----
        __builtin_amdgcn_s_setprio(1);
        #pragma unroll
        for (int kk = 0; kk < 2; ++kk) {
            const int kb = kk * 64 + kgrp * 16;
            bf16x8 af[4], bb[4];
            #pragma unroll
            for (int m = 0; m < 4; ++m)
                af[m] = *(const bf16x8*)(lA + swz(wr * 64 + m * 16 + lrow, kb));
            #pragma unroll
            for (int n = 0; n < 4; ++n)
                bb[n] = *(const bf16x8*)(lB + swz(wc * 64 + n * 16 + lrow, kb));
            #pragma unroll
            for (int m = 0; m < 4; ++m)
                #pragma unroll
                for (int n = 0; n < 4; ++n)
                    acc[m][n] = __builtin_amdgcn_mfma_f32_16x16x32_bf16(
                        af[m], bb[n], acc[m][n], 0, 0, 0);
        }
        __builtin_amdgcn_s_setprio(0);

        // ---- cvt (compiler adds counted vmcnt) + ds_write into buf[cur^1],
        //      retire writes, then ONE raw barrier (no vmcnt drain) ----
        if (kt + 1 < KTILES) {
            char* sA = lds + (cur ^ 1) * BUFSZ;
            char* sB = sA + TILESZ;
            #pragma unroll
            for (int i = 0; i < 8; ++i)
                *(unsigned long long*)(sA + swz(sr + i * 16, sc4 * 8)) = pack4bf(pA[i]);
            #pragma unroll
            for (int i = 0; i < 8; ++i)
                *(unsigned long long*)(sB + swz(sr + i * 16, sc4 * 8)) = pack4bf(pB[i]);
            asm volatile("s_waitcnt lgkmcnt(0)" ::: "memory");
            __builtin_amdgcn_sched_barrier(0);
            __builtin_amdgcn_s_barrier();
            __builtin_amdgcn_sched_barrier(0);
        }
        // last iteration: no staging, no barrier — epilogue is register+global only
    }

    // ---- epilogue: C/D layout col=lane&15, row=(lane>>4)*4+j ----
    #pragma unroll
    for (int m = 0; m < 4; ++m) {
        #pragma unroll
        for (int j = 0; j < 4; ++j) {
            int row = row0 + wr * 64 + m * 16 + kgrp * 4 + j;
            if (row < endg) {
                #pragma unroll
                for (int n = 0; n < 4; ++n) {
                    int col = n0 + wc * 64 + n * 16 + lrow;
                    out[(size_t)row * DOUT + col] = acc[m][n][j];
                }
            }
        }
    }
}

extern "C" void kernel_launch(void* const* d_in, const int* in_sizes, int n_in,
                              void* d_out, int out_size, void* d_ws, size_t ws_size,
                              hipStream_t stream) {
    const float* x    = (const float*)d_in[0];
    const int*   offs = (const int*)d_in[1];
    const float* w    = (const float*)d_in[2];
    float* out = (float*)d_out;

    dim3 grid(DOUT / BN, NT / BM + NG, 1);
    grouped_gemm_bf16<<<grid, 256, 0, stream>>>(x, offs, w, out);
}